// Round 8
// baseline (26.007 us; speedup 1.0000x reference)
//
#include <hip/hip_runtime.h>

// WICC dynamic-connectivity step, fused edge-update + scatter-add.
// B=16, D=1024, E=D*D. All f32.
// Outputs concatenated: phi_out [B*D] then edge_state_next [B*E].
//
// Round 8: R7 + depth-2 es prefetch. One wave = one dst x 4 batches.
// es: 3-slot rotating register buffer, 2 rows in flight (8x16B loads/wave).
// state: depth-1 ping-pong (L1-resident anyway). J row: registers, loaded
// once. Fully unrolled -> all buffer indices static. 1024 blocks (4/CU),
// raw v_sqrt_f32, no LDS/barriers/atomics/nt.

#define WICC_B 16
#define WICC_D 1024

typedef float vfloat4 __attribute__((ext_vector_type(4)));

__device__ __forceinline__ float fast_sqrt(float x) {
    return __builtin_amdgcn_sqrtf(x);   // v_sqrt_f32, ~1 ULP
}

__global__ __launch_bounds__(256, 4) void wicc_step_kernel(
    const float* __restrict__ state,     // [B, D]
    const float* __restrict__ phi,       // [B, D]
    const float* __restrict__ J,         // [D, D] (dst, src)
    const float* __restrict__ es_in,     // [B, E]
    float* __restrict__ phi_out,         // [B, D]
    float* __restrict__ es_out)          // [B, E]
{
    // 1024 blocks. Block i -> XCD (i&7) (round-robin dispatch). Each XCD owns
    // dst slab [xcd*128, xcd*128+128): 512 KB of J, L2-resident.
    const int i    = blockIdx.x;          // 0..1023
    const int xcd  = i & 7;
    const int si   = i >> 3;              // 0..127
    const int bgrp = si >> 5;             // 0..3   (b in [4*bgrp, 4*bgrp+4))
    const int dgrp = si & 31;             // 0..31

    const int wave = threadIdx.x >> 6;    // 0..3
    const int lane = threadIdx.x & 63;
    const int dst  = xcd * 128 + dgrp * 4 + wave;

    // J row: registers, reused for all 4 rows.
    const vfloat4* __restrict__ jrow = reinterpret_cast<const vfloat4*>(J + (size_t)dst * WICC_D);
    vfloat4 j4[4];
    #pragma unroll
    for (int k = 0; k < 4; ++k) j4[k] = jrow[lane + 64 * k];

    const float J_IN = 0.38f, GP = 1e-3f, OMG = 1.0f - 1e-3f, BIAS = 2.0f, TH = 0.1675f;

    vfloat4 e[3][4];   // rotating depth-2 es prefetch (static-indexed via unroll)
    vfloat4 s[2][4];   // depth-1 state ping-pong

    const int b0 = bgrp * 4;
    const size_t erow0 = ((size_t)b0 * WICC_D * WICC_D + (size_t)dst * WICC_D) >> 2;
    const size_t estep = ((size_t)WICC_D * WICC_D) >> 2;     // row stride per batch

    // Prologue: es rows 0,1 in flight; state row 0.
    {
        const vfloat4* __restrict__ er0 = reinterpret_cast<const vfloat4*>(es_in) + erow0;
        const vfloat4* __restrict__ er1 = er0 + estep;
        const vfloat4* __restrict__ sr0 = reinterpret_cast<const vfloat4*>(state + (size_t)b0 * WICC_D);
        #pragma unroll
        for (int k = 0; k < 4; ++k) e[0][k] = er0[lane + 64 * k];
        #pragma unroll
        for (int k = 0; k < 4; ++k) e[1][k] = er1[lane + 64 * k];
        #pragma unroll
        for (int k = 0; k < 4; ++k) s[0][k] = sr0[lane + 64 * k];
    }

    #pragma unroll
    for (int it = 0; it < 4; ++it) {
        const int b = b0 + it;

        // Prefetch es row it+2 (depth 2) and state row it+1 (depth 1).
        if (it < 2) {
            const vfloat4* __restrict__ ern =
                reinterpret_cast<const vfloat4*>(es_in) + erow0 + (size_t)(it + 2) * estep;
            #pragma unroll
            for (int k = 0; k < 4; ++k) e[(it + 2) % 3][k] = ern[lane + 64 * k];
        }
        if (it < 3) {
            const vfloat4* __restrict__ srn =
                reinterpret_cast<const vfloat4*>(state + (size_t)(b + 1) * WICC_D);
            #pragma unroll
            for (int k = 0; k < 4; ++k) s[(it + 1) & 1][k] = srn[lane + 64 * k];
        }

        const int node = b * WICC_D + dst;
        const float phv = phi[node];
        vfloat4* __restrict__ orow = reinterpret_cast<vfloat4*>(es_out) + erow0 + (size_t)it * estep;

        float acc = 0.0f;
        #pragma unroll
        for (int k = 0; k < 4; ++k) {
            vfloat4 o4;
            #pragma unroll
            for (int c = 0; c < 4; ++c) {
                const float x  = s[it & 1][k][c] * J_IN;
                const float jj = j4[k][c];
                const float es = e[it % 3][k][c];
                const float pa = x + jj;
                const float pb = x - jj;
                const float ca = BIAS - es;
                const float cb = BIAS + es;
                const float ra = fast_sqrt(fmaxf(ca * ca - 1.0f, 0.0f));
                const float rb = fast_sqrt(fmaxf(cb * cb - 1.0f, 0.0f));
                const float ga = (fabsf(pa) > TH) ? ra : 0.0f;
                const float gb = (fabsf(pb) > TH) ? rb : 0.0f;
                const float esn = fmaf(es, OMG, GP * (ga - gb));   // es*(1-GM) + GP*(ga-gb)
                o4[c] = esn;
                acc += esn;
            }
            orow[lane + 64 * k] = o4;   // fire-and-forget
        }

        // In-register wave reduction: no LDS, no barrier.
        #pragma unroll
        for (int off = 32; off > 0; off >>= 1)
            acc += __shfl_down(acc, off, 64);

        if (lane == 0)
            phi_out[node] = phv + 0.38f * acc;   // J_OUT = 0.38
    }
}

extern "C" void kernel_launch(void* const* d_in, const int* in_sizes, int n_in,
                              void* d_out, int out_size, void* d_ws, size_t ws_size,
                              hipStream_t stream) {
    const float* state = (const float*)d_in[0];   // [B, D]
    const float* phi   = (const float*)d_in[1];   // [B, D]
    const float* J     = (const float*)d_in[2];   // [D, D]
    const float* es    = (const float*)d_in[3];   // [B, E]

    float* phi_out = (float*)d_out;                         // [B*D]
    float* es_out  = (float*)d_out + WICC_B * WICC_D;       // [B*E]

    wicc_step_kernel<<<dim3(1024), dim3(256), 0, stream>>>(
        state, phi, J, es, phi_out, es_out);
}

// Round 9
// 24.910 us; speedup vs baseline: 1.0440x; 1.0440x over previous
//
#include <hip/hip_runtime.h>

// WICC dynamic-connectivity step, fused edge-update + scatter-add.
// B=16, D=1024, E=D*D. All f32.
// Outputs concatenated: phi_out [B*D] then edge_state_next [B*E].
//
// Round 9: occupancy push. 2048 blocks (8192 waves; grid no longer caps
// waves/CU at 16). Wave = one dst x 2 batches, es depth-1 ping-pong.
// VGPR diet: J reloaded per row (L2-resident XCD slab), state loaded at
// use (L1-resident row). __launch_bounds__(256,6) -> <=85 VGPR -> 24
// waves/CU. No LDS/barriers/atomics/nt; raw v_sqrt_f32.

#define WICC_B 16
#define WICC_D 1024

typedef float vfloat4 __attribute__((ext_vector_type(4)));

__device__ __forceinline__ float fast_sqrt(float x) {
    return __builtin_amdgcn_sqrtf(x);   // v_sqrt_f32, ~1 ULP
}

__global__ __launch_bounds__(256, 6) void wicc_step_kernel(
    const float* __restrict__ state,     // [B, D]
    const float* __restrict__ phi,       // [B, D]
    const float* __restrict__ J,         // [D, D] (dst, src)
    const float* __restrict__ es_in,     // [B, E]
    float* __restrict__ phi_out,         // [B, D]
    float* __restrict__ es_out)          // [B, E]
{
    // 2048 blocks. Block i -> XCD (i&7) (round-robin dispatch). Each XCD owns
    // dst slab [xcd*128, xcd*128+128): 512 KB of J, L2-resident.
    const int i    = blockIdx.x;          // 0..2047
    const int xcd  = i & 7;
    const int si   = i >> 3;              // 0..255
    const int bgrp = si >> 5;             // 0..7   (b in {2*bgrp, 2*bgrp+1})
    const int dgrp = si & 31;             // 0..31

    const int wave = threadIdx.x >> 6;    // 0..3
    const int lane = threadIdx.x & 63;
    const int dst  = xcd * 128 + dgrp * 4 + wave;

    const float J_IN = 0.38f, GP = 1e-3f, OMG = 1.0f - 1e-3f, BIAS = 2.0f, TH = 0.1675f;

    const int b0 = bgrp * 2;
    const size_t erow0 = ((size_t)b0 * WICC_D * WICC_D + (size_t)dst * WICC_D) >> 2;
    const size_t estep = ((size_t)WICC_D * WICC_D) >> 2;     // es row stride per batch

    vfloat4 e[2][4];   // depth-1 ping-pong (static-indexed via unroll)

    // Prologue: es row 0 in flight.
    {
        const vfloat4* __restrict__ er0 = reinterpret_cast<const vfloat4*>(es_in) + erow0;
        #pragma unroll
        for (int k = 0; k < 4; ++k) e[0][k] = er0[lane + 64 * k];
    }

    #pragma unroll
    for (int it = 0; it < 2; ++it) {
        const int b = b0 + it;

        // Prefetch next row's es (depth 1).
        if (it < 1) {
            const vfloat4* __restrict__ ern =
                reinterpret_cast<const vfloat4*>(es_in) + erow0 + (size_t)(it + 1) * estep;
            #pragma unroll
            for (int k = 0; k < 4; ++k) e[it ^ 1][k] = ern[lane + 64 * k];
        }

        // J row (L2-hit: XCD slab) and state row (L1-hit: shared per b) at use.
        const vfloat4* __restrict__ jrow = reinterpret_cast<const vfloat4*>(J + (size_t)dst * WICC_D);
        const vfloat4* __restrict__ srow = reinterpret_cast<const vfloat4*>(state + (size_t)b * WICC_D);

        const int node = b * WICC_D + dst;
        const float phv = phi[node];
        vfloat4* __restrict__ orow = reinterpret_cast<vfloat4*>(es_out) + erow0 + (size_t)it * estep;

        float acc = 0.0f;
        #pragma unroll
        for (int k = 0; k < 4; ++k) {
            const vfloat4 j4 = jrow[lane + 64 * k];
            const vfloat4 s4 = srow[lane + 64 * k];
            vfloat4 o4;
            #pragma unroll
            for (int c = 0; c < 4; ++c) {
                const float x  = s4[c] * J_IN;
                const float jj = j4[c];
                const float es = e[it][k][c];
                const float pa = x + jj;
                const float pb = x - jj;
                const float ca = BIAS - es;
                const float cb = BIAS + es;
                const float ra = fast_sqrt(fmaxf(ca * ca - 1.0f, 0.0f));
                const float rb = fast_sqrt(fmaxf(cb * cb - 1.0f, 0.0f));
                const float ga = (fabsf(pa) > TH) ? ra : 0.0f;
                const float gb = (fabsf(pb) > TH) ? rb : 0.0f;
                const float esn = fmaf(es, OMG, GP * (ga - gb));   // es*(1-GM) + GP*(ga-gb)
                o4[c] = esn;
                acc += esn;
            }
            orow[lane + 64 * k] = o4;   // fire-and-forget
        }

        // In-register wave reduction: no LDS, no barrier.
        #pragma unroll
        for (int off = 32; off > 0; off >>= 1)
            acc += __shfl_down(acc, off, 64);

        if (lane == 0)
            phi_out[node] = phv + 0.38f * acc;   // J_OUT = 0.38
    }
}

extern "C" void kernel_launch(void* const* d_in, const int* in_sizes, int n_in,
                              void* d_out, int out_size, void* d_ws, size_t ws_size,
                              hipStream_t stream) {
    const float* state = (const float*)d_in[0];   // [B, D]
    const float* phi   = (const float*)d_in[1];   // [B, D]
    const float* J     = (const float*)d_in[2];   // [D, D]
    const float* es    = (const float*)d_in[3];   // [B, E]

    float* phi_out = (float*)d_out;                         // [B*D]
    float* es_out  = (float*)d_out + WICC_B * WICC_D;       // [B*E]

    wicc_step_kernel<<<dim3(2048), dim3(256), 0, stream>>>(
        state, phi, J, es, phi_out, es_out);
}

// Round 10
// 24.787 us; speedup vs baseline: 1.0492x; 1.0050x over previous
//
#include <hip/hip_runtime.h>

// WICC dynamic-connectivity step, fused edge-update + scatter-add.
// B=16, D=1024, E=D*D. All f32.
// Outputs concatenated: phi_out [B*D] then edge_state_next [B*E].
//
// Round 10: R9 with the occupancy pushed from 6 to 8 blocks/CU
// (__launch_bounds__(256,8) -> <=64 VGPR -> 32 waves/CU, the chip max).
// Everything else identical: 2048 blocks, wave = one dst x 2 batches,
// es depth-1 ping-pong, J/state loaded at use (L2/L1-resident), XCD slab
// remap, raw v_sqrt_f32, no LDS/barriers/atomics/nt.

#define WICC_B 16
#define WICC_D 1024

typedef float vfloat4 __attribute__((ext_vector_type(4)));

__device__ __forceinline__ float fast_sqrt(float x) {
    return __builtin_amdgcn_sqrtf(x);   // v_sqrt_f32, ~1 ULP
}

__global__ __launch_bounds__(256, 8) void wicc_step_kernel(
    const float* __restrict__ state,     // [B, D]
    const float* __restrict__ phi,       // [B, D]
    const float* __restrict__ J,         // [D, D] (dst, src)
    const float* __restrict__ es_in,     // [B, E]
    float* __restrict__ phi_out,         // [B, D]
    float* __restrict__ es_out)          // [B, E]
{
    // 2048 blocks. Block i -> XCD (i&7) (round-robin dispatch). Each XCD owns
    // dst slab [xcd*128, xcd*128+128): 512 KB of J, L2-resident.
    const int i    = blockIdx.x;          // 0..2047
    const int xcd  = i & 7;
    const int si   = i >> 3;              // 0..255
    const int bgrp = si >> 5;             // 0..7   (b in {2*bgrp, 2*bgrp+1})
    const int dgrp = si & 31;             // 0..31

    const int wave = threadIdx.x >> 6;    // 0..3
    const int lane = threadIdx.x & 63;
    const int dst  = xcd * 128 + dgrp * 4 + wave;

    const float J_IN = 0.38f, GP = 1e-3f, OMG = 1.0f - 1e-3f, BIAS = 2.0f, TH = 0.1675f;

    const int b0 = bgrp * 2;
    const size_t erow0 = ((size_t)b0 * WICC_D * WICC_D + (size_t)dst * WICC_D) >> 2;
    const size_t estep = ((size_t)WICC_D * WICC_D) >> 2;     // es row stride per batch

    vfloat4 e[2][4];   // depth-1 ping-pong (static-indexed via unroll)

    // Prologue: es row 0 in flight.
    {
        const vfloat4* __restrict__ er0 = reinterpret_cast<const vfloat4*>(es_in) + erow0;
        #pragma unroll
        for (int k = 0; k < 4; ++k) e[0][k] = er0[lane + 64 * k];
    }

    #pragma unroll
    for (int it = 0; it < 2; ++it) {
        const int b = b0 + it;

        // Prefetch next row's es (depth 1).
        if (it < 1) {
            const vfloat4* __restrict__ ern =
                reinterpret_cast<const vfloat4*>(es_in) + erow0 + (size_t)(it + 1) * estep;
            #pragma unroll
            for (int k = 0; k < 4; ++k) e[it ^ 1][k] = ern[lane + 64 * k];
        }

        // J row (L2-hit: XCD slab) and state row (L1-hit: shared per b) at use.
        const vfloat4* __restrict__ jrow = reinterpret_cast<const vfloat4*>(J + (size_t)dst * WICC_D);
        const vfloat4* __restrict__ srow = reinterpret_cast<const vfloat4*>(state + (size_t)b * WICC_D);

        const int node = b * WICC_D + dst;
        const float phv = phi[node];
        vfloat4* __restrict__ orow = reinterpret_cast<vfloat4*>(es_out) + erow0 + (size_t)it * estep;

        float acc = 0.0f;
        #pragma unroll
        for (int k = 0; k < 4; ++k) {
            const vfloat4 j4 = jrow[lane + 64 * k];
            const vfloat4 s4 = srow[lane + 64 * k];
            vfloat4 o4;
            #pragma unroll
            for (int c = 0; c < 4; ++c) {
                const float x  = s4[c] * J_IN;
                const float jj = j4[c];
                const float es = e[it][k][c];
                const float pa = x + jj;
                const float pb = x - jj;
                const float ca = BIAS - es;
                const float cb = BIAS + es;
                const float ra = fast_sqrt(fmaxf(ca * ca - 1.0f, 0.0f));
                const float rb = fast_sqrt(fmaxf(cb * cb - 1.0f, 0.0f));
                const float ga = (fabsf(pa) > TH) ? ra : 0.0f;
                const float gb = (fabsf(pb) > TH) ? rb : 0.0f;
                const float esn = fmaf(es, OMG, GP * (ga - gb));   // es*(1-GM) + GP*(ga-gb)
                o4[c] = esn;
                acc += esn;
            }
            orow[lane + 64 * k] = o4;   // fire-and-forget
        }

        // In-register wave reduction: no LDS, no barrier.
        #pragma unroll
        for (int off = 32; off > 0; off >>= 1)
            acc += __shfl_down(acc, off, 64);

        if (lane == 0)
            phi_out[node] = phv + 0.38f * acc;   // J_OUT = 0.38
    }
}

extern "C" void kernel_launch(void* const* d_in, const int* in_sizes, int n_in,
                              void* d_out, int out_size, void* d_ws, size_t ws_size,
                              hipStream_t stream) {
    const float* state = (const float*)d_in[0];   // [B, D]
    const float* phi   = (const float*)d_in[1];   // [B, D]
    const float* J     = (const float*)d_in[2];   // [D, D]
    const float* es    = (const float*)d_in[3];   // [B, E]

    float* phi_out = (float*)d_out;                         // [B*D]
    float* es_out  = (float*)d_out + WICC_B * WICC_D;       // [B*E]

    wicc_step_kernel<<<dim3(2048), dim3(256), 0, stream>>>(
        state, phi, J, es, phi_out, es_out);
}